// Round 3
// baseline (202.759 us; speedup 1.0000x reference)
//
#include <hip/hip_runtime.h>

#define CMIN -1024.0f
#define CMAX 1016.0f
#define NBLK 512
#define NTHR 256

__device__ __forceinline__ float clampv(float x) {
    return fminf(fmaxf(x, CMIN), CMAX);
}

// ---------------------------------------------------------------------------
// Single persistent kernel. 512 blocks x 256 threads = 131072 threads, all
// trivially co-resident (device capacity 524288 threads), so a grid-wide
// spin on a device-scope counter cannot deadlock.
//
//  ws layout (16 B, memset to 0 before launch):
//   ws[0], ws[1] : per-channel DC sums (float)
//   ws[2]        : done-counter (uint, reinterpreted)
// ---------------------------------------------------------------------------
__global__ void __launch_bounds__(NTHR)
fused_all(const float4* __restrict__ y4, const float4* __restrict__ c4,
          const float*  __restrict__ c,  float4* __restrict__ outy,
          float4* __restrict__ outc, float* __restrict__ ws,
          unsigned* __restrict__ done,
          int ynvec, int cnvec, int dc_per_ch, float inv_count) {
    const int tid  = threadIdx.x;
    const int gtid = blockIdx.x * NTHR + tid;   // 0 .. 131071

    // ---- Phase A: DC partial sums. Each global thread owns exactly one of
    // the 131072 DC elements (flat index gtid*64 in c). Blocks 0..255 are
    // wholly channel 0, blocks 256..511 wholly channel 1.
    {
        float v = clampv(c[(size_t)gtid * 64]);
        #pragma unroll
        for (int off = 32; off > 0; off >>= 1)
            v += __shfl_down(v, off, 64);
        __shared__ float smem[NTHR / 64];
        if ((tid & 63) == 0) smem[tid >> 6] = v;
        __syncthreads();
        if (tid == 0) {
            float s = 0.f;
            #pragma unroll
            for (int w = 0; w < NTHR / 64; ++w) s += smem[w];
            const int ch = (gtid < dc_per_ch) ? 0 : 1;
            atomicAdd(&ws[ch], s);        // device-scope by default
            __threadfence();              // make the sum visible device-wide
            atomicAdd(done, 1u);
        }
    }

    // ---- Phase B: y elementwise (streams ~134 MB; hides phase-A drain) ----
    for (int i = gtid; i < ynvec; i += NBLK * NTHR) {
        float4 v = y4[i];
        v.x = clampv(clampv(v.x) * 1.9f);
        v.y = clampv(clampv(v.y) * 1.9f);
        v.z = clampv(clampv(v.z) * 1.9f);
        v.w = clampv(clampv(v.w) * 1.9f);
        outy[i] = v;
    }

    // ---- Wait for all blocks' DC sums, broadcast means via LDS ----
    __shared__ float sdc[2];
    if (tid == 0) {
        while (__hip_atomic_load(done, __ATOMIC_ACQUIRE,
                                 __HIP_MEMORY_SCOPE_AGENT) < (unsigned)NBLK) {}
        sdc[0] = __hip_atomic_load(&ws[0], __ATOMIC_RELAXED,
                                   __HIP_MEMORY_SCOPE_AGENT) * inv_count;
        sdc[1] = __hip_atomic_load(&ws[1], __ATOMIC_RELAXED,
                                   __HIP_MEMORY_SCOPE_AGENT) * inv_count;
    }
    __syncthreads();
    const float adj0 = -0.9f * sdc[0];
    const float adj1 = -0.9f * sdc[1];

    // ---- Phase C: c elementwise ----
    const int chalf = cnvec >> 1;
    for (int i = gtid; i < cnvec; i += NBLK * NTHR) {
        float4 v = c4[i];
        float4 r;
        r.x = clampv(v.x) * 1.9f;
        r.y = clampv(v.y) * 1.9f;
        r.z = clampv(v.z) * 1.9f;
        r.w = clampv(v.w) * 1.9f;
        if ((i & 15) == 0)                 // DC element of an 8x8 block
            r.x += (i < chalf) ? adj0 : adj1;
        r.x = clampv(r.x);
        r.y = clampv(r.y);
        r.z = clampv(r.z);
        r.w = clampv(r.w);
        outc[i] = r;
    }
}

extern "C" void kernel_launch(void* const* d_in, const int* in_sizes, int n_in,
                              void* d_out, int out_size, void* d_ws, size_t ws_size,
                              hipStream_t stream) {
    const float* y = (const float*)d_in[0];
    const float* c = (const float*)d_in[1];
    float* out = (float*)d_out;

    const int yN = in_sizes[0];             // 16777216
    const int cN = in_sizes[1];             // 8388608

    float* ws = (float*)d_ws;               // [sum0, sum1, done]
    unsigned* done = (unsigned*)(ws + 2);

    // zero accumulators + counter (d_ws is re-poisoned to 0xAA every launch)
    hipMemsetAsync(ws, 0, 16, stream);

    const int ynvec = yN / 4;               // 4194304
    const int cnvec = cN / 4;               // 2097152
    const int dc_per_ch = cN / 64 / 2;      // 65536
    const float inv_count = 1.0f / (float)dc_per_ch;

    fused_all<<<NBLK, NTHR, 0, stream>>>(
        (const float4*)y, (const float4*)c, c,
        (float4*)out, (float4*)(out + yN),
        ws, done, ynvec, cnvec, dc_per_ch, inv_count);
}